// Round 11
// baseline (237.925 us; speedup 1.0000x reference)
//
#include <hip/hip_runtime.h>
#include <math.h>

// Problem constants (reference: B=4, T=2048, C=1024, H=16, d=64)
#define BB   4
#define TT   2048
#define CC   1024
#define HH   16
#define DD   64
#define MM   (BB*TT)     // 8192 rows
#define NQKV (3*CC)      // 3072
#define LCH  128         // attention chunk length
#define NCH  (TT/LCH)    // 16 chunks per (b,h)
#define EPSF 1e-6f

// LDS strides (in shorts). chunk_state keeps 136 (4 blk/CU already).
// chunk_attn uses 130 (R19): total LDS 56576->54080 B => 3 blocks/CU (+50% TLP).
#define PST  136         // chunk_state P-equiv stride (unused there, kept for Vt)
#define VTST 136         // chunk_state V-transposed tile row stride
#define PSTA  130        // chunk_attn P tile row stride
#define VTSTA 130        // chunk_attn V-transposed tile row stride

typedef __bf16 bf16x8 __attribute__((ext_vector_type(8)));
typedef float  floatx4 __attribute__((ext_vector_type(4)));

__device__ __forceinline__ unsigned short f2bf(float f) {
  union { float f; unsigned int u; } v; v.f = f;
  unsigned int r = v.u + 0x7fffu + ((v.u >> 16) & 1u); // RNE
  return (unsigned short)(r >> 16);
}
__device__ __forceinline__ float bf2f(unsigned short s) {
  union { unsigned int u; float f; } v; v.u = ((unsigned int)s) << 16;
  return v.f;
}
__device__ __forceinline__ float featmap(float v) {
  // elu(v)+1
  return v > 0.f ? v + 1.f : __expf(v);
}
// async global->LDS, 16B per lane; LDS dest = wave-uniform base + lane*16
__device__ __forceinline__ void gld_lds_b128(const unsigned short* g, unsigned short* l) {
  __builtin_amdgcn_global_load_lds(
      (const __attribute__((address_space(1))) unsigned int*)g,
      (__attribute__((address_space(3))) unsigned int*)l, 16, 0, 0);
}

// ---------------- prep: x->bf16 + both weight transposes, one kernel ----------------
// R18 vectorized transpose body (measured neutral vs scalar; kept — G13-sound).
__device__ __forceinline__ void transpose_cvt_body(const float* __restrict__ W,
                                                   unsigned short* __restrict__ out,
                                                   int R, int Cc, int bx32, int by32, int tid) {
  __shared__ float tile[32][33];
  int bx = bx32 * 32, by = by32 * 32;
  {
    int r = tid >> 3, c4 = tid & 7;
    float4 f = *(const float4*)&W[(size_t)(by + r) * Cc + bx + c4 * 4];
    tile[r][c4 * 4 + 0] = f.x; tile[r][c4 * 4 + 1] = f.y;
    tile[r][c4 * 4 + 2] = f.z; tile[r][c4 * 4 + 3] = f.w;
  }
  __syncthreads();
  {
    int i = tid >> 3, t4 = tid & 7;
    ushort4 o;
    o.x = f2bf(tile[t4 * 4 + 0][i]);
    o.y = f2bf(tile[t4 * 4 + 1][i]);
    o.z = f2bf(tile[t4 * 4 + 2][i]);
    o.w = f2bf(tile[t4 * 4 + 3][i]);
    *(ushort4*)&out[(size_t)(bx + i) * R + by + t4 * 4] = o;
  }
}

// grid: [0,8192) cvt_x | [8192,11264) W_attn transpose | [11264,12288) W_proj transpose
__global__ __launch_bounds__(256) void prep_kernel(
    const float* __restrict__ x, unsigned short* __restrict__ xb,
    const float* __restrict__ Wa, unsigned short* __restrict__ WaT,
    const float* __restrict__ Wp, unsigned short* __restrict__ WpT) {
  int blk = blockIdx.x, tid = threadIdx.x;
  if (blk < 8192) {
    int i = (blk * 256 + tid) * 4;
    float4 f = *(const float4*)(x + i);
    ushort4 o;
    o.x = f2bf(f.x); o.y = f2bf(f.y); o.z = f2bf(f.z); o.w = f2bf(f.w);
    *(ushort4*)(xb + i) = o;
  } else if (blk < 8192 + 3072) {
    int t = blk - 8192;                       // 96 x 32
    transpose_cvt_body(Wa, WaT, CC, NQKV, t % 96, t / 96, tid);
  } else {
    int t = blk - 11264;                      // 32 x 32
    transpose_cvt_body(Wp, WpT, CC, CC, t % 32, t / 32, tid);
  }
}

// ---------------- GEMM 1: qkv = x @ W_attn + b, split + feature map ----------------
// R11 schedule + T1 XCD-chunked block swizzle (verified: FETCH 71.8->57.5MB).
#define BKQ   32
#define ASLT  (256 * BKQ)   // 8192 shorts / slot
#define BSLT  (192 * BKQ)   // 6144 shorts / slot
#define NT_Q  (CC / BKQ)    // 32 K-tiles

__global__ __launch_bounds__(512, 2) void gemm_qkv_kernel(
    const unsigned short* __restrict__ A, const unsigned short* __restrict__ Bt,
    const float* __restrict__ bias,
    unsigned short* __restrict__ qh, unsigned short* __restrict__ kh,
    unsigned short* __restrict__ vh) {
  extern __shared__ __align__(16) unsigned short lds[];
  unsigned short* Ar = lds;                 // [4][256][32]
  unsigned short* Br = lds + 4 * ASLT;      // [4][192][32]

  const int tid = threadIdx.x;
  const int wave = tid >> 6, lane = tid & 63;
  const int lr = lane & 15, lq = lane >> 4;
  // T1 swizzle: lin = y*16+x (HW x-fastest); XCD k owns 64 consecutive new ids.
  const int lin = blockIdx.y * 16 + blockIdx.x;
  const int lin2 = (lin & 7) * 64 + (lin >> 3);
  const int m0 = (lin2 >> 4) * 256, n0 = (lin2 & 15) * 192;
  const int wm = (wave >> 2) * 128, wn = (wave & 3) * 48;

  const int srow = wave * 16 + (lane >> 2);
  const int cs = (lane & 3) ^ ((lane >> 3) & 3);
  const unsigned short* gA0 = A  + (size_t)(m0 + srow) * CC + cs * 8;
  const unsigned short* gB0 = Bt + (size_t)(n0 + srow) * CC + cs * 8;
  unsigned short* const stA = Ar + wave * 512;   // wave-uniform LDS dest base
  unsigned short* const stB = Br + wave * 512;
  const bool bhi = (wave < 4);                   // waves 0-3 stage B rows 128..191

  const int chunk = lq ^ ((lr >> 1) & 3);
  const int roA = (wm + lr) * BKQ + chunk * 8;
  const int roB = (wn + lr) * BKQ + chunk * 8;

  floatx4 acc[3][8] = {};   // [n-frag][m-frag], transposed-C convention

#define QSTAGE_A(tt) do {                                      \
    const unsigned short* g_ = gA0 + (tt) * BKQ;               \
    unsigned short* d_ = stA + ((tt) & 3) * ASLT;              \
    gld_lds_b128(g_, d_);                                      \
    gld_lds_b128(g_ + (size_t)128 * CC, d_ + 4096);            \
  } while (0)
#define QSTAGE_B(tt) do {                                      \
    const unsigned short* g_ = gB0 + (tt) * BKQ;               \
    unsigned short* d_ = stB + ((tt) & 3) * BSLT;              \
    gld_lds_b128(g_, d_);                                      \
    if (bhi) gld_lds_b128(g_ + (size_t)128 * CC, d_ + 4096);   \
  } while (0)

  // prologue: stage K-tiles 0,1,2; wait tile 0 (keep tiles 1,2 in flight)
  QSTAGE_A(0); QSTAGE_B(0);
  QSTAGE_A(1); QSTAGE_B(1);
  QSTAGE_A(2); QSTAGE_B(2);
  asm volatile("s_waitcnt vmcnt(6)" ::: "memory");
  __builtin_amdgcn_s_barrier();

  #pragma unroll 4
  for (int t = 0; t < NT_Q; ++t) {
    const unsigned short* sA = Ar + (t & 3) * ASLT + roA;
    const unsigned short* sB = Br + (t & 3) * BSLT + roB;
    bf16x8 an[3], bm[8];
    #pragma unroll
    for (int i = 0; i < 3; i++) an[i] = *(const bf16x8*)(sB + i * (16 * BKQ));
    #pragma unroll
    for (int j = 0; j < 8; j++) bm[j] = *(const bf16x8*)(sA + j * (16 * BKQ));
    if (t < NT_Q - 3) { QSTAGE_A(t + 3); QSTAGE_B(t + 3); }
    __builtin_amdgcn_s_barrier();
    asm volatile("s_waitcnt lgkmcnt(0)" ::: "memory");
    __builtin_amdgcn_s_setprio(1);
    #pragma unroll
    for (int i = 0; i < 3; i++)
      #pragma unroll
      for (int j = 0; j < 8; j++)
        acc[i][j] = __builtin_amdgcn_mfma_f32_16x16x32_bf16(an[i], bm[j], acc[i][j], 0, 0, 0);
    __builtin_amdgcn_s_setprio(0);
    // boundary: next tile's data must be resident; counted (never 0 until drain)
    if (t < NT_Q - 3)        asm volatile("s_waitcnt vmcnt(6)" ::: "memory");
    else if (t == NT_Q - 3)  asm volatile("s_waitcnt vmcnt(3)" ::: "memory");
    else if (t == NT_Q - 2)  asm volatile("s_waitcnt vmcnt(0)" ::: "memory");
    __builtin_amdgcn_s_barrier();
  }
#undef QSTAGE_A
#undef QSTAGE_B

  // epilogue: transposed C/D -> lane holds 4 consecutive n (channels), m = col.
  unsigned short* dstv[3];
  size_t qoff[3];
  float4 bi[3];
  bool feat[3];
  #pragma unroll
  for (int i = 0; i < 3; i++) {
    const int n = n0 + wn + i * 16 + lq * 4;
    dstv[i] = (n < 1024) ? qh : (n < 2048) ? kh : vh;
    feat[i] = (n < 2048);
    const int h = (n & 1023) >> 6, dd = n & 63;
    qoff[i] = (size_t)h * (TT * DD) + dd;
    bi[i] = *(const float4*)&bias[n];
  }
  #pragma unroll
  for (int j = 0; j < 8; j++) {
    const int m = m0 + wm + j * 16 + lr;
    const int b = m >> 11, tg = m & 2047;
    const size_t pj = (size_t)b * (HH * TT * DD) + (size_t)tg * DD;
    #pragma unroll
    for (int i = 0; i < 3; i++) {
      float v0 = acc[i][j][0] + bi[i].x, v1 = acc[i][j][1] + bi[i].y;
      float v2 = acc[i][j][2] + bi[i].z, v3 = acc[i][j][3] + bi[i].w;
      if (feat[i]) { v0 = featmap(v0); v1 = featmap(v1); v2 = featmap(v2); v3 = featmap(v3); }
      ushort4 o; o.x = f2bf(v0); o.y = f2bf(v1); o.z = f2bf(v2); o.w = f2bf(v3);
      *(ushort4*)&dstv[i][pj + qoff[i]] = o;
    }
  }
}

// ---------------- GEMM 2: out = y @ W_proj + b_proj (fp32 out) ----------------
// R12 schedule + T1 swizzle (grid 4x64 = 256 = 8 XCDs x 32, bijective).
#define PBK   32
#define PASLT (128 * PBK)   // 4096 shorts / slot
#define PBSLT (256 * PBK)   // 8192 shorts / slot
#define NT_P  (CC / PBK)    // 32 K-tiles

__global__ __launch_bounds__(512, 2) void gemm_proj_kernel(
    const unsigned short* __restrict__ A, const unsigned short* __restrict__ Bt,
    const float* __restrict__ bias, float* __restrict__ out) {
  extern __shared__ __align__(16) unsigned short lds[];
  unsigned short* Ar = lds;                 // [4][128][32]
  unsigned short* Br = lds + 4 * PASLT;     // [4][256][32]

  const int tid = threadIdx.x;
  const int wave = tid >> 6, lane = tid & 63;
  const int lr = lane & 15, lq = lane >> 4;
  const int lin = blockIdx.y * 4 + blockIdx.x;
  const int lin2 = (lin & 7) * 32 + (lin >> 3);
  const int m0 = (lin2 >> 2) * 128, n0 = (lin2 & 3) * 256;
  const int wm = (wave >> 2) * 64, wn = (wave & 3) * 64;

  const int srow = wave * 16 + (lane >> 2);
  const int cs = (lane & 3) ^ ((lane >> 3) & 3);
  const unsigned short* gA0 = A  + (size_t)(m0 + srow) * CC + cs * 8;
  const unsigned short* gB0 = Bt + (size_t)(n0 + srow) * CC + cs * 8;
  unsigned short* const stA = Ar + wave * 512;
  unsigned short* const stB = Br + wave * 512;

  const int chunk = lq ^ ((lr >> 1) & 3);
  const int roA = (wm + lr) * PBK + chunk * 8;
  const int roB = (wn + lr) * PBK + chunk * 8;

  floatx4 acc[4][4] = {};   // [n-frag][m-frag], transposed-C convention

#define PSTAGE(tt) do {                                        \
    const unsigned short* ga_ = gA0 + (tt) * PBK;              \
    unsigned short* da_ = stA + ((tt) & 3) * PASLT;            \
    gld_lds_b128(ga_, da_);                                    \
    const unsigned short* gb_ = gB0 + (tt) * PBK;              \
    unsigned short* db_ = stB + ((tt) & 3) * PBSLT;            \
    gld_lds_b128(gb_, db_);                                    \
    gld_lds_b128(gb_ + (size_t)128 * CC, db_ + 4096);          \
  } while (0)

  PSTAGE(0); PSTAGE(1); PSTAGE(2);
  asm volatile("s_waitcnt vmcnt(6)" ::: "memory");
  __builtin_amdgcn_s_barrier();

  #pragma unroll 4
  for (int t = 0; t < NT_P; ++t) {
    const unsigned short* sA = Ar + (t & 3) * PASLT + roA;
    const unsigned short* sB = Br + (t & 3) * PBSLT + roB;
    bf16x8 an[4], bm[4];
    #pragma unroll
    for (int i = 0; i < 4; i++) an[i] = *(const bf16x8*)(sB + i * (16 * PBK));
    #pragma unroll
    for (int j = 0; j < 4; j++) bm[j] = *(const bf16x8*)(sA + j * (16 * PBK));
    if (t < NT_P - 3) PSTAGE(t + 3);
    __builtin_amdgcn_s_barrier();
    asm volatile("s_waitcnt lgkmcnt(0)" ::: "memory");
    __builtin_amdgcn_s_setprio(1);
    #pragma unroll
    for (int i = 0; i < 4; i++)
      #pragma unroll
      for (int j = 0; j < 4; j++)
        acc[i][j] = __builtin_amdgcn_mfma_f32_16x16x32_bf16(an[i], bm[j], acc[i][j], 0, 0, 0);
    __builtin_amdgcn_s_setprio(0);
    if (t < NT_P - 3)        asm volatile("s_waitcnt vmcnt(6)" ::: "memory");
    else if (t == NT_P - 3)  asm volatile("s_waitcnt vmcnt(3)" ::: "memory");
    else if (t == NT_P - 2)  asm volatile("s_waitcnt vmcnt(0)" ::: "memory");
    __builtin_amdgcn_s_barrier();
  }
#undef PSTAGE

  // epilogue: lane holds 4 consecutive n; m = col (lr). float4 stores + bias.
  #pragma unroll
  for (int i = 0; i < 4; i++) {
    const int n = n0 + wn + i * 16 + lq * 4;
    const float4 bi = *(const float4*)&bias[n];
    #pragma unroll
    for (int j = 0; j < 4; j++) {
      const int m = m0 + wm + j * 16 + lr;
      float4 o;
      o.x = acc[i][j][0] + bi.x; o.y = acc[i][j][1] + bi.y;
      o.z = acc[i][j][2] + bi.z; o.w = acc[i][j][3] + bi.w;
      *(float4*)&out[(size_t)m * CC + n] = o;
    }
  }
}

// ---------------- Phase A: per-chunk KV state (MFMA) ----------------
// R15 version (issue-early, full column coverage), strides untouched (4 blk/CU).
__global__ __launch_bounds__(256) void chunk_state_kernel(
    const unsigned short* __restrict__ kh, const unsigned short* __restrict__ vh,
    float* __restrict__ KVx) {
  __shared__ __align__(16) unsigned short Kt[64 * VTST];   // K^T: Kt[i][t]
  __shared__ __align__(16) unsigned short Vt[80 * VTST];   // V^T + ones/zero rows
  int blk = blockIdx.x;
  int bh = blk / NCH, c = blk % NCH;
  int tid = threadIdx.x;
  const unsigned short* kp = kh + ((size_t)bh * TT + c * LCH) * DD;
  const unsigned short* vp = vh + ((size_t)bh * TT + c * LCH) * DD;
  {
    int t = tid & 127, j0 = (tid >> 7) * 8;
    union { uint4 u; unsigned short s[8]; } wk[4], wv[4];
    #pragma unroll
    for (int ii = 0; ii < 4; ii++) {
      wk[ii].u = *(const uint4*)&kp[(size_t)t * DD + j0 + ii * 16];
      wv[ii].u = *(const uint4*)&vp[(size_t)t * DD + j0 + ii * 16];
    }
    #pragma unroll
    for (int ii = 0; ii < 4; ii++) {
      const int j8 = j0 + ii * 16;
      #pragma unroll
      for (int jj = 0; jj < 8; jj++) {
        Kt[(j8 + jj) * VTST + t] = wk[ii].s[jj];
        Vt[(j8 + jj) * VTST + t] = wv[ii].s[jj];
      }
    }
  }
  for (int e = tid; e < 16 * 128; e += 256) {
    int rr = e >> 7, n = e & 127;
    Vt[(64 + rr) * VTST + n] = (rr == 0) ? (unsigned short)0x3F80 : (unsigned short)0;
  }
  __syncthreads();
  int wave = tid >> 6, lane = tid & 63;
  int lr = lane & 15, lq = lane >> 4;
  int i0 = wave * 16;             // wave's 16-row band of K^T (i dimension)
  floatx4 acc[5] = {};
  #pragma unroll
  for (int kk = 0; kk < 4; kk++) {
    bf16x8 a = *(const bf16x8*)&Kt[(i0 + lr) * VTST + kk * 32 + lq * 8];
    #pragma unroll
    for (int jt = 0; jt < 5; jt++) {
      bf16x8 b = *(const bf16x8*)&Vt[(jt * 16 + lr) * VTST + kk * 32 + lq * 8];
      acc[jt] = __builtin_amdgcn_mfma_f32_16x16x32_bf16(a, b, acc[jt], 0, 0, 0);
    }
  }
  // C/D: col(j) = lane&15, row(i) = i0 + lq*4 + r; store transposed [j][i].
  float* o = KVx + (size_t)blk * 5120;
  #pragma unroll
  for (int jt = 0; jt < 5; jt++)
    *(float4*)&o[(jt * 16 + lr) * 64 + i0 + lq * 4] = *(float4*)&acc[jt];
}

// ---------------- Phase B: exclusive prefix over chunks -> bf16 SP_ext ----------
// R11: fully unrolled — all 16 chunk loads issued up front, then scan+stores.
__global__ __launch_bounds__(256) void prefix_state_kernel(const float* __restrict__ KVx,
                                                           unsigned short* __restrict__ SPb) {
  int bh = blockIdx.x / 5, jb = blockIdx.x % 5;
  int e = jb * 1024 + threadIdx.x * 4;
  size_t base0 = ((size_t)bh * NCH) * 5120 + e;
  float4 v[NCH];
  #pragma unroll
  for (int c = 0; c < NCH; c++)
    v[c] = *(const float4*)&KVx[base0 + (size_t)c * 5120];
  float r0 = 0.f, r1 = 0.f, r2 = 0.f, r3 = 0.f;
  #pragma unroll
  for (int c = 0; c < NCH; c++) {
    ushort4 o;
    o.x = f2bf(r0); o.y = f2bf(r1); o.z = f2bf(r2); o.w = f2bf(r3);
    *(ushort4*)&SPb[base0 + (size_t)c * 5120] = o;
    r0 += v[c].x; r1 += v[c].y; r2 += v[c].z; r3 += v[c].w;
  }
}

// ---------------- Phase C: per-chunk attention output (MFMA, transposed) ----------
// R19: P/Vt strides 136->130 => LDS 56576->54080 B => 3 blocks/CU (was 2).
// Mechanism: chunk_attn is a barrier-separated latency chain; R13 showed more
// waves PER BLOCK hurt (skew), but more independent BLOCKS per CU interleave
// across each other's barrier stalls. Strides are layout-only: math identical.
// Bank pattern at stride 130 (65 dw == 1 mod 32): <=4-way worst case (m136: 1.58x).
__global__ __launch_bounds__(256) void chunk_attn_kernel(
    const unsigned short* __restrict__ qh, const unsigned short* __restrict__ kh,
    const unsigned short* __restrict__ vh, const unsigned short* __restrict__ SPb,
    unsigned short* __restrict__ yb) {
  // region A: Qs[128][64]@0, Ks[128][64]@8192 (16384 shorts); P[128][PSTA]=16640
  // shorts overlays region A after Qs/Ks dead. Vt[80][VTSTA] @16640.
  __shared__ __align__(16) unsigned short lds[16640 + 80 * VTSTA];  // 54080 B
  unsigned short* Qs = lds;                       // [128][64] swizzled
  unsigned short* Ks = lds + 8192;                // [128][64] swizzled
  unsigned short* P  = lds;                       // [128][PSTA] (after Qs/Ks dead)
  unsigned short* Vt = lds + 16640;               // [80][VTSTA]

  int blk = blockIdx.x;
  int bh = blk / NCH, c = blk % NCH;
  int b = bh / HH, h = bh % HH;
  int tid = threadIdx.x;
  const unsigned short* qp = qh + ((size_t)bh * TT + c * LCH) * DD;
  const unsigned short* kp = kh + ((size_t)bh * TT + c * LCH) * DD;
  const unsigned short* vp = vh + ((size_t)bh * TT + c * LCH) * DD;

  int wave = tid >> 6, lane = tid & 63;
  int lr = lane & 15, lq = lane >> 4;
  int mbase = wave * 32;

  // 1) V -> regs first (oldest in vmcnt order)
  const int vt = tid & 127, vj0 = (tid >> 7) * 8;
  uint4 wv[4];
  #pragma unroll
  for (int ii = 0; ii < 4; ii++)
    wv[ii] = *(const uint4*)&vp[(size_t)vt * DD + vj0 + ii * 16];
  asm volatile("" ::: "memory");   // keep V loads issued before the gld_lds

  // 2) async Q,K -> LDS: wave stages rows [wave*32, +32) = 4 glds each.
  {
    const int grow8 = lane >> 3;               // 0..7
    const int gc = (lane & 7) ^ grow8;         // swizzled source 16B-chunk
    const unsigned short* gq = qp + (size_t)(wave * 32 + grow8) * DD + gc * 8;
    const unsigned short* gk = kp + (size_t)(wave * 32 + grow8) * DD + gc * 8;
    unsigned short* dq = Qs + wave * 32 * DD;  // wave-uniform dest
    unsigned short* dk = Ks + wave * 32 * DD;
    #pragma unroll
    for (int g = 0; g < 4; g++) {
      gld_lds_b128(gq + (size_t)g * 8 * DD, dq + g * 512);
      gld_lds_b128(gk + (size_t)g * 8 * DD, dk + g * 512);
    }
  }

  // 3) V transpose writes (compiler waits only the 4 V loads; 8 glds in flight)
  #pragma unroll
  for (int ii = 0; ii < 4; ii++) {
    union { uint4 u; unsigned short s[8]; } w; w.u = wv[ii];
    const int j8 = vj0 + ii * 16;
    #pragma unroll
    for (int jj = 0; jj < 8; jj++) Vt[(j8 + jj) * VTSTA + vt] = w.s[jj];
  }
  // ones row (j=64) and zero rows (65..79)
  for (int e = tid; e < 16 * 128; e += 256) {
    int rr = e >> 7, n = e & 127;
    Vt[(64 + rr) * VTSTA + n] = (rr == 0) ? (unsigned short)0x3F80 : (unsigned short)0;
  }
  asm volatile("s_waitcnt vmcnt(0)" ::: "memory");  // Q/K resident in LDS
  __syncthreads();

  // Q frags (swizzled chunk read) for this wave's two 16-row t-tiles
  bf16x8 aq[2][2];
  #pragma unroll
  for (int i = 0; i < 2; i++)
    #pragma unroll
    for (int kk = 0; kk < 2; kk++)
      aq[i][kk] = *(const bf16x8*)&Qs[(mbase + i * 16 + lr) * DD +
                                      ((((kk << 2) + lq) ^ (lr & 7)) << 3)];

  // accT[jt][it]: D[j][t], rows j = jt*16 + lq*4 + r, cols t = mbase + it*16 + lr
  floatx4 accT[5][2] = {};
  // inter-chunk: A = SPb rows [j][i], B = Q rows [t][i]
  const unsigned short* spb = SPb + (size_t)blk * (80 * 64);
  #pragma unroll
  for (int jt = 0; jt < 5; jt++)
    #pragma unroll
    for (int kk = 0; kk < 2; kk++) {
      bf16x8 asp = *(const bf16x8*)&spb[(jt * 16 + lr) * 64 + kk * 32 + lq * 8];
      accT[jt][0] = __builtin_amdgcn_mfma_f32_16x16x32_bf16(asp, aq[0][kk], accT[jt][0], 0, 0, 0);
      accT[jt][1] = __builtin_amdgcn_mfma_f32_16x16x32_bf16(asp, aq[1][kk], accT[jt][1], 0, 0, 0);
    }
  // intra-chunk scores: S = Q @ K^T (row=t(q), col=t'(k))
  floatx4 sacc[2][8] = {};
  #pragma unroll
  for (int nt = 0; nt < 8; nt++)
    #pragma unroll
    for (int kk = 0; kk < 2; kk++) {
      bf16x8 bk = *(const bf16x8*)&Ks[(nt * 16 + lr) * DD +
                                      ((((kk << 2) + lq) ^ (lr & 7)) << 3)];
      sacc[0][nt] = __builtin_amdgcn_mfma_f32_16x16x32_bf16(aq[0][kk], bk, sacc[0][nt], 0, 0, 0);
      sacc[1][nt] = __builtin_amdgcn_mfma_f32_16x16x32_bf16(aq[1][kk], bk, sacc[1][nt], 0, 0, 0);
    }
  __syncthreads();  // everyone done reading Qs/Ks before P overwrites them

  // causal mask + bf16 round, C-layout -> LDS P[t][t']
  #pragma unroll
  for (int i = 0; i < 2; i++)
    #pragma unroll
    for (int nt = 0; nt < 8; nt++) {
      int col = nt * 16 + lr;
      #pragma unroll
      for (int r = 0; r < 4; r++) {
        int m = mbase + i * 16 + lq * 4 + r;
        float v = (col <= m) ? sacc[i][nt][r] : 0.f;
        P[m * PSTA + col] = f2bf(v);
      }
    }
  __syncthreads();

  // accT += (P @ V_ext)^T: A = Vt rows [j][t'], B = P rows [t][t']
  #pragma unroll
  for (int kk4 = 0; kk4 < 4; kk4++) {
    bf16x8 bp0 = *(const bf16x8*)&P[(mbase + lr) * PSTA + kk4 * 32 + lq * 8];
    bf16x8 bp1 = *(const bf16x8*)&P[(mbase + 16 + lr) * PSTA + kk4 * 32 + lq * 8];
    #pragma unroll
    for (int jt = 0; jt < 5; jt++) {
      bf16x8 av = *(const bf16x8*)&Vt[(jt * 16 + lr) * VTSTA + kk4 * 32 + lq * 8];
      accT[jt][0] = __builtin_amdgcn_mfma_f32_16x16x32_bf16(av, bp0, accT[jt][0], 0, 0, 0);
      accT[jt][1] = __builtin_amdgcn_mfma_f32_16x16x32_bf16(av, bp1, accT[jt][1], 0, 0, 0);
    }
  }

  // epilogue: den = row 64 = accT[4][it] reg0 on lanes lq=0, col=t=lane&15.
  #pragma unroll
  for (int it = 0; it < 2; it++) {
    float den = __shfl(accT[4][it][0], lr, 64);
    float inv = 1.f / (den + EPSF);
    int tg = c * LCH + mbase + it * 16 + lr;
    size_t base = ((size_t)b * TT + tg) * CC + h * DD;
    #pragma unroll
    for (int jt = 0; jt < 4; jt++) {
      ushort4 o;
      o.x = f2bf(accT[jt][it][0] * inv);
      o.y = f2bf(accT[jt][it][1] * inv);
      o.z = f2bf(accT[jt][it][2] * inv);
      o.w = f2bf(accT[jt][it][3] * inv);
      *(ushort4*)&yb[base + jt * 16 + lq * 4] = o;
    }
  }
}

// ---------------- host launch ----------------
extern "C" void kernel_launch(void* const* d_in, const int* in_sizes, int n_in,
                              void* d_out, int out_size, void* d_ws, size_t ws_size,
                              hipStream_t stream) {
  const float* x      = (const float*)d_in[0];
  const float* W_attn = (const float*)d_in[1];
  const float* b_attn = (const float*)d_in[2];
  const float* W_proj = (const float*)d_in[3];
  const float* b_proj = (const float*)d_in[4];
  float* out = (float*)d_out;

  char* ws = (char*)d_ws;
  size_t off = 0;
  auto alloc = [&](size_t bytes) -> char* {
    char* p = ws + off;
    off += (bytes + 255) & ~(size_t)255;
    return p;
  };
  unsigned short* xb  = (unsigned short*)alloc((size_t)MM * CC * 2);   // reused as yb
  unsigned short* WaT = (unsigned short*)alloc((size_t)NQKV * CC * 2);
  unsigned short* WpT = (unsigned short*)alloc((size_t)CC * CC * 2);
  unsigned short* qh  = (unsigned short*)alloc((size_t)MM * CC * 2);
  unsigned short* kh  = (unsigned short*)alloc((size_t)MM * CC * 2);
  unsigned short* vh  = (unsigned short*)alloc((size_t)MM * CC * 2);
  float* KVx = (float*)alloc((size_t)BB * HH * NCH * 80 * 64 * 4);
  unsigned short* SPb = (unsigned short*)alloc((size_t)BB * HH * NCH * 80 * 64 * 2);
  unsigned short* yb = xb;  // xb dead after gemm_qkv

  static bool s_attr_done = false;
  if (!s_attr_done) {
    (void)hipFuncSetAttribute((const void*)gemm_qkv_kernel,
                              hipFuncAttributeMaxDynamicSharedMemorySize, 114688);
    (void)hipFuncSetAttribute((const void*)gemm_proj_kernel,
                              hipFuncAttributeMaxDynamicSharedMemorySize, 98304);
    s_attr_done = true;
  }

  prep_kernel<<<12288, 256, 0, stream>>>(x, xb, W_attn, WaT, W_proj, WpT);
  gemm_qkv_kernel<<<dim3(NQKV / 192, MM / 256), 512, 114688, stream>>>(xb, WaT, b_attn, qh, kh, vh);
  chunk_state_kernel<<<BB * HH * NCH, 256, 0, stream>>>(kh, vh, KVx);
  prefix_state_kernel<<<BB * HH * 5, 256, 0, stream>>>(KVx, SPb);
  chunk_attn_kernel<<<BB * HH * NCH, 256, 0, stream>>>(qh, kh, vh, SPb, yb);
  gemm_proj_kernel<<<dim3(CC / 256, MM / 128), 512, 98304, stream>>>(yb, WpT, b_proj, out);
}

// Round 12
// 228.284 us; speedup vs baseline: 1.0422x; 1.0422x over previous
//
#include <hip/hip_runtime.h>
#include <math.h>

// Problem constants (reference: B=4, T=2048, C=1024, H=16, d=64)
#define BB   4
#define TT   2048
#define CC   1024
#define HH   16
#define DD   64
#define MM   (BB*TT)     // 8192 rows
#define NQKV (3*CC)      // 3072
#define LCH  128         // attention chunk length
#define NCH  (TT/LCH)    // 16 chunks per (b,h)
#define EPSF 1e-6f

// LDS strides (in shorts). chunk_state keeps 136 (4 blk/CU already).
// chunk_attn uses 130 (R19): total LDS 56576->54080 B => 3 blocks/CU (+50% TLP).
#define PST  136         // chunk_state P-equiv stride (unused there, kept for Vt)
#define VTST 136         // chunk_state V-transposed tile row stride
#define PSTA  130        // chunk_attn P tile row stride
#define VTSTA 130        // chunk_attn V-transposed tile row stride

typedef __bf16 bf16x8 __attribute__((ext_vector_type(8)));
typedef float  floatx4 __attribute__((ext_vector_type(4)));

__device__ __forceinline__ unsigned short f2bf(float f) {
  union { float f; unsigned int u; } v; v.f = f;
  unsigned int r = v.u + 0x7fffu + ((v.u >> 16) & 1u); // RNE
  return (unsigned short)(r >> 16);
}
__device__ __forceinline__ float bf2f(unsigned short s) {
  union { unsigned int u; float f; } v; v.u = ((unsigned int)s) << 16;
  return v.f;
}
__device__ __forceinline__ float featmap(float v) {
  // elu(v)+1
  return v > 0.f ? v + 1.f : __expf(v);
}
// async global->LDS, 16B per lane; LDS dest = wave-uniform base + lane*16
__device__ __forceinline__ void gld_lds_b128(const unsigned short* g, unsigned short* l) {
  __builtin_amdgcn_global_load_lds(
      (const __attribute__((address_space(1))) unsigned int*)g,
      (__attribute__((address_space(3))) unsigned int*)l, 16, 0, 0);
}

// ---------------- prep: x->bf16 + both weight transposes, one kernel ----------------
// R18 vectorized transpose body (measured neutral vs scalar; kept — G13-sound).
__device__ __forceinline__ void transpose_cvt_body(const float* __restrict__ W,
                                                   unsigned short* __restrict__ out,
                                                   int R, int Cc, int bx32, int by32, int tid) {
  __shared__ float tile[32][33];
  int bx = bx32 * 32, by = by32 * 32;
  {
    int r = tid >> 3, c4 = tid & 7;
    float4 f = *(const float4*)&W[(size_t)(by + r) * Cc + bx + c4 * 4];
    tile[r][c4 * 4 + 0] = f.x; tile[r][c4 * 4 + 1] = f.y;
    tile[r][c4 * 4 + 2] = f.z; tile[r][c4 * 4 + 3] = f.w;
  }
  __syncthreads();
  {
    int i = tid >> 3, t4 = tid & 7;
    ushort4 o;
    o.x = f2bf(tile[t4 * 4 + 0][i]);
    o.y = f2bf(tile[t4 * 4 + 1][i]);
    o.z = f2bf(tile[t4 * 4 + 2][i]);
    o.w = f2bf(tile[t4 * 4 + 3][i]);
    *(ushort4*)&out[(size_t)(bx + i) * R + by + t4 * 4] = o;
  }
}

// grid: [0,8192) cvt_x | [8192,11264) W_attn transpose | [11264,12288) W_proj transpose
__global__ __launch_bounds__(256) void prep_kernel(
    const float* __restrict__ x, unsigned short* __restrict__ xb,
    const float* __restrict__ Wa, unsigned short* __restrict__ WaT,
    const float* __restrict__ Wp, unsigned short* __restrict__ WpT) {
  int blk = blockIdx.x, tid = threadIdx.x;
  if (blk < 8192) {
    int i = (blk * 256 + tid) * 4;
    float4 f = *(const float4*)(x + i);
    ushort4 o;
    o.x = f2bf(f.x); o.y = f2bf(f.y); o.z = f2bf(f.z); o.w = f2bf(f.w);
    *(ushort4*)(xb + i) = o;
  } else if (blk < 8192 + 3072) {
    int t = blk - 8192;                       // 96 x 32
    transpose_cvt_body(Wa, WaT, CC, NQKV, t % 96, t / 96, tid);
  } else {
    int t = blk - 11264;                      // 32 x 32
    transpose_cvt_body(Wp, WpT, CC, CC, t % 32, t / 32, tid);
  }
}

// ---------------- GEMM 1: qkv = x @ W_attn + b, split + feature map ----------------
// R11 schedule + T1 XCD-chunked block swizzle (verified: FETCH 71.8->57.5MB).
#define BKQ   32
#define ASLT  (256 * BKQ)   // 8192 shorts / slot
#define BSLT  (192 * BKQ)   // 6144 shorts / slot
#define NT_Q  (CC / BKQ)    // 32 K-tiles

__global__ __launch_bounds__(512, 2) void gemm_qkv_kernel(
    const unsigned short* __restrict__ A, const unsigned short* __restrict__ Bt,
    const float* __restrict__ bias,
    unsigned short* __restrict__ qh, unsigned short* __restrict__ kh,
    unsigned short* __restrict__ vh) {
  extern __shared__ __align__(16) unsigned short lds[];
  unsigned short* Ar = lds;                 // [4][256][32]
  unsigned short* Br = lds + 4 * ASLT;      // [4][192][32]

  const int tid = threadIdx.x;
  const int wave = tid >> 6, lane = tid & 63;
  const int lr = lane & 15, lq = lane >> 4;
  // T1 swizzle: lin = y*16+x (HW x-fastest); XCD k owns 64 consecutive new ids.
  const int lin = blockIdx.y * 16 + blockIdx.x;
  const int lin2 = (lin & 7) * 64 + (lin >> 3);
  const int m0 = (lin2 >> 4) * 256, n0 = (lin2 & 15) * 192;
  const int wm = (wave >> 2) * 128, wn = (wave & 3) * 48;

  const int srow = wave * 16 + (lane >> 2);
  const int cs = (lane & 3) ^ ((lane >> 3) & 3);
  const unsigned short* gA0 = A  + (size_t)(m0 + srow) * CC + cs * 8;
  const unsigned short* gB0 = Bt + (size_t)(n0 + srow) * CC + cs * 8;
  unsigned short* const stA = Ar + wave * 512;   // wave-uniform LDS dest base
  unsigned short* const stB = Br + wave * 512;
  const bool bhi = (wave < 4);                   // waves 0-3 stage B rows 128..191

  const int chunk = lq ^ ((lr >> 1) & 3);
  const int roA = (wm + lr) * BKQ + chunk * 8;
  const int roB = (wn + lr) * BKQ + chunk * 8;

  floatx4 acc[3][8] = {};   // [n-frag][m-frag], transposed-C convention

#define QSTAGE_A(tt) do {                                      \
    const unsigned short* g_ = gA0 + (tt) * BKQ;               \
    unsigned short* d_ = stA + ((tt) & 3) * ASLT;              \
    gld_lds_b128(g_, d_);                                      \
    gld_lds_b128(g_ + (size_t)128 * CC, d_ + 4096);            \
  } while (0)
#define QSTAGE_B(tt) do {                                      \
    const unsigned short* g_ = gB0 + (tt) * BKQ;               \
    unsigned short* d_ = stB + ((tt) & 3) * BSLT;              \
    gld_lds_b128(g_, d_);                                      \
    if (bhi) gld_lds_b128(g_ + (size_t)128 * CC, d_ + 4096);   \
  } while (0)

  // prologue: stage K-tiles 0,1,2; wait tile 0 (keep tiles 1,2 in flight)
  QSTAGE_A(0); QSTAGE_B(0);
  QSTAGE_A(1); QSTAGE_B(1);
  QSTAGE_A(2); QSTAGE_B(2);
  asm volatile("s_waitcnt vmcnt(6)" ::: "memory");
  __builtin_amdgcn_s_barrier();

  #pragma unroll 4
  for (int t = 0; t < NT_Q; ++t) {
    const unsigned short* sA = Ar + (t & 3) * ASLT + roA;
    const unsigned short* sB = Br + (t & 3) * BSLT + roB;
    bf16x8 an[3], bm[8];
    #pragma unroll
    for (int i = 0; i < 3; i++) an[i] = *(const bf16x8*)(sB + i * (16 * BKQ));
    #pragma unroll
    for (int j = 0; j < 8; j++) bm[j] = *(const bf16x8*)(sA + j * (16 * BKQ));
    if (t < NT_Q - 3) { QSTAGE_A(t + 3); QSTAGE_B(t + 3); }
    __builtin_amdgcn_s_barrier();
    asm volatile("s_waitcnt lgkmcnt(0)" ::: "memory");
    __builtin_amdgcn_s_setprio(1);
    #pragma unroll
    for (int i = 0; i < 3; i++)
      #pragma unroll
      for (int j = 0; j < 8; j++)
        acc[i][j] = __builtin_amdgcn_mfma_f32_16x16x32_bf16(an[i], bm[j], acc[i][j], 0, 0, 0);
    __builtin_amdgcn_s_setprio(0);
    // boundary: next tile's data must be resident; counted (never 0 until drain)
    if (t < NT_Q - 3)        asm volatile("s_waitcnt vmcnt(6)" ::: "memory");
    else if (t == NT_Q - 3)  asm volatile("s_waitcnt vmcnt(3)" ::: "memory");
    else if (t == NT_Q - 2)  asm volatile("s_waitcnt vmcnt(0)" ::: "memory");
    __builtin_amdgcn_s_barrier();
  }
#undef QSTAGE_A
#undef QSTAGE_B

  // epilogue: transposed C/D -> lane holds 4 consecutive n (channels), m = col.
  unsigned short* dstv[3];
  size_t qoff[3];
  float4 bi[3];
  bool feat[3];
  #pragma unroll
  for (int i = 0; i < 3; i++) {
    const int n = n0 + wn + i * 16 + lq * 4;
    dstv[i] = (n < 1024) ? qh : (n < 2048) ? kh : vh;
    feat[i] = (n < 2048);
    const int h = (n & 1023) >> 6, dd = n & 63;
    qoff[i] = (size_t)h * (TT * DD) + dd;
    bi[i] = *(const float4*)&bias[n];
  }
  #pragma unroll
  for (int j = 0; j < 8; j++) {
    const int m = m0 + wm + j * 16 + lr;
    const int b = m >> 11, tg = m & 2047;
    const size_t pj = (size_t)b * (HH * TT * DD) + (size_t)tg * DD;
    #pragma unroll
    for (int i = 0; i < 3; i++) {
      float v0 = acc[i][j][0] + bi[i].x, v1 = acc[i][j][1] + bi[i].y;
      float v2 = acc[i][j][2] + bi[i].z, v3 = acc[i][j][3] + bi[i].w;
      if (feat[i]) { v0 = featmap(v0); v1 = featmap(v1); v2 = featmap(v2); v3 = featmap(v3); }
      ushort4 o; o.x = f2bf(v0); o.y = f2bf(v1); o.z = f2bf(v2); o.w = f2bf(v3);
      *(ushort4*)&dstv[i][pj + qoff[i]] = o;
    }
  }
}

// ---------------- GEMM 2: out = y @ W_proj + b_proj (fp32 out) ----------------
// R12 schedule + T1 swizzle (grid 4x64 = 256 = 8 XCDs x 32, bijective).
#define PBK   32
#define PASLT (128 * PBK)   // 4096 shorts / slot
#define PBSLT (256 * PBK)   // 8192 shorts / slot
#define NT_P  (CC / PBK)    // 32 K-tiles

__global__ __launch_bounds__(512, 2) void gemm_proj_kernel(
    const unsigned short* __restrict__ A, const unsigned short* __restrict__ Bt,
    const float* __restrict__ bias, float* __restrict__ out) {
  extern __shared__ __align__(16) unsigned short lds[];
  unsigned short* Ar = lds;                 // [4][128][32]
  unsigned short* Br = lds + 4 * PASLT;     // [4][256][32]

  const int tid = threadIdx.x;
  const int wave = tid >> 6, lane = tid & 63;
  const int lr = lane & 15, lq = lane >> 4;
  const int lin = blockIdx.y * 4 + blockIdx.x;
  const int lin2 = (lin & 7) * 32 + (lin >> 3);
  const int m0 = (lin2 >> 2) * 128, n0 = (lin2 & 3) * 256;
  const int wm = (wave >> 2) * 64, wn = (wave & 3) * 64;

  const int srow = wave * 16 + (lane >> 2);
  const int cs = (lane & 3) ^ ((lane >> 3) & 3);
  const unsigned short* gA0 = A  + (size_t)(m0 + srow) * CC + cs * 8;
  const unsigned short* gB0 = Bt + (size_t)(n0 + srow) * CC + cs * 8;
  unsigned short* const stA = Ar + wave * 512;
  unsigned short* const stB = Br + wave * 512;

  const int chunk = lq ^ ((lr >> 1) & 3);
  const int roA = (wm + lr) * PBK + chunk * 8;
  const int roB = (wn + lr) * PBK + chunk * 8;

  floatx4 acc[4][4] = {};   // [n-frag][m-frag], transposed-C convention

#define PSTAGE(tt) do {                                        \
    const unsigned short* ga_ = gA0 + (tt) * PBK;              \
    unsigned short* da_ = stA + ((tt) & 3) * PASLT;            \
    gld_lds_b128(ga_, da_);                                    \
    const unsigned short* gb_ = gB0 + (tt) * PBK;              \
    unsigned short* db_ = stB + ((tt) & 3) * PBSLT;            \
    gld_lds_b128(gb_, db_);                                    \
    gld_lds_b128(gb_ + (size_t)128 * CC, db_ + 4096);          \
  } while (0)

  PSTAGE(0); PSTAGE(1); PSTAGE(2);
  asm volatile("s_waitcnt vmcnt(6)" ::: "memory");
  __builtin_amdgcn_s_barrier();

  #pragma unroll 4
  for (int t = 0; t < NT_P; ++t) {
    const unsigned short* sA = Ar + (t & 3) * PASLT + roA;
    const unsigned short* sB = Br + (t & 3) * PBSLT + roB;
    bf16x8 an[4], bm[4];
    #pragma unroll
    for (int i = 0; i < 4; i++) an[i] = *(const bf16x8*)(sB + i * (16 * PBK));
    #pragma unroll
    for (int j = 0; j < 4; j++) bm[j] = *(const bf16x8*)(sA + j * (16 * PBK));
    if (t < NT_P - 3) PSTAGE(t + 3);
    __builtin_amdgcn_s_barrier();
    asm volatile("s_waitcnt lgkmcnt(0)" ::: "memory");
    __builtin_amdgcn_s_setprio(1);
    #pragma unroll
    for (int i = 0; i < 4; i++)
      #pragma unroll
      for (int j = 0; j < 4; j++)
        acc[i][j] = __builtin_amdgcn_mfma_f32_16x16x32_bf16(an[i], bm[j], acc[i][j], 0, 0, 0);
    __builtin_amdgcn_s_setprio(0);
    if (t < NT_P - 3)        asm volatile("s_waitcnt vmcnt(6)" ::: "memory");
    else if (t == NT_P - 3)  asm volatile("s_waitcnt vmcnt(3)" ::: "memory");
    else if (t == NT_P - 2)  asm volatile("s_waitcnt vmcnt(0)" ::: "memory");
    __builtin_amdgcn_s_barrier();
  }
#undef PSTAGE

  // epilogue: lane holds 4 consecutive n; m = col (lr). float4 stores + bias.
  #pragma unroll
  for (int i = 0; i < 4; i++) {
    const int n = n0 + wn + i * 16 + lq * 4;
    const float4 bi = *(const float4*)&bias[n];
    #pragma unroll
    for (int j = 0; j < 4; j++) {
      const int m = m0 + wm + j * 16 + lr;
      float4 o;
      o.x = acc[i][j][0] + bi.x; o.y = acc[i][j][1] + bi.y;
      o.z = acc[i][j][2] + bi.z; o.w = acc[i][j][3] + bi.w;
      *(float4*)&out[(size_t)m * CC + n] = o;
    }
  }
}

// ---------------- Phase A: per-chunk KV state (MFMA) ----------------
// R15 version (issue-early, full column coverage), strides untouched (4 blk/CU).
__global__ __launch_bounds__(256) void chunk_state_kernel(
    const unsigned short* __restrict__ kh, const unsigned short* __restrict__ vh,
    float* __restrict__ KVx) {
  __shared__ __align__(16) unsigned short Kt[64 * VTST];   // K^T: Kt[i][t]
  __shared__ __align__(16) unsigned short Vt[80 * VTST];   // V^T + ones/zero rows
  int blk = blockIdx.x;
  int bh = blk / NCH, c = blk % NCH;
  int tid = threadIdx.x;
  const unsigned short* kp = kh + ((size_t)bh * TT + c * LCH) * DD;
  const unsigned short* vp = vh + ((size_t)bh * TT + c * LCH) * DD;
  {
    int t = tid & 127, j0 = (tid >> 7) * 8;
    union { uint4 u; unsigned short s[8]; } wk[4], wv[4];
    #pragma unroll
    for (int ii = 0; ii < 4; ii++) {
      wk[ii].u = *(const uint4*)&kp[(size_t)t * DD + j0 + ii * 16];
      wv[ii].u = *(const uint4*)&vp[(size_t)t * DD + j0 + ii * 16];
    }
    #pragma unroll
    for (int ii = 0; ii < 4; ii++) {
      const int j8 = j0 + ii * 16;
      #pragma unroll
      for (int jj = 0; jj < 8; jj++) {
        Kt[(j8 + jj) * VTST + t] = wk[ii].s[jj];
        Vt[(j8 + jj) * VTST + t] = wv[ii].s[jj];
      }
    }
  }
  for (int e = tid; e < 16 * 128; e += 256) {
    int rr = e >> 7, n = e & 127;
    Vt[(64 + rr) * VTST + n] = (rr == 0) ? (unsigned short)0x3F80 : (unsigned short)0;
  }
  __syncthreads();
  int wave = tid >> 6, lane = tid & 63;
  int lr = lane & 15, lq = lane >> 4;
  int i0 = wave * 16;             // wave's 16-row band of K^T (i dimension)
  floatx4 acc[5] = {};
  #pragma unroll
  for (int kk = 0; kk < 4; kk++) {
    bf16x8 a = *(const bf16x8*)&Kt[(i0 + lr) * VTST + kk * 32 + lq * 8];
    #pragma unroll
    for (int jt = 0; jt < 5; jt++) {
      bf16x8 b = *(const bf16x8*)&Vt[(jt * 16 + lr) * VTST + kk * 32 + lq * 8];
      acc[jt] = __builtin_amdgcn_mfma_f32_16x16x32_bf16(a, b, acc[jt], 0, 0, 0);
    }
  }
  // C/D: col(j) = lane&15, row(i) = i0 + lq*4 + r; store transposed [j][i].
  float* o = KVx + (size_t)blk * 5120;
  #pragma unroll
  for (int jt = 0; jt < 5; jt++)
    *(float4*)&o[(jt * 16 + lr) * 64 + i0 + lq * 4] = *(float4*)&acc[jt];
}

// ---------------- Phase B: exclusive prefix over chunks -> bf16 SP_ext ----------
// R11: fully unrolled — all 16 chunk loads issued up front, then scan+stores.
__global__ __launch_bounds__(256) void prefix_state_kernel(const float* __restrict__ KVx,
                                                           unsigned short* __restrict__ SPb) {
  int bh = blockIdx.x / 5, jb = blockIdx.x % 5;
  int e = jb * 1024 + threadIdx.x * 4;
  size_t base0 = ((size_t)bh * NCH) * 5120 + e;
  float4 v[NCH];
  #pragma unroll
  for (int c = 0; c < NCH; c++)
    v[c] = *(const float4*)&KVx[base0 + (size_t)c * 5120];
  float r0 = 0.f, r1 = 0.f, r2 = 0.f, r3 = 0.f;
  #pragma unroll
  for (int c = 0; c < NCH; c++) {
    ushort4 o;
    o.x = f2bf(r0); o.y = f2bf(r1); o.z = f2bf(r2); o.w = f2bf(r3);
    *(ushort4*)&SPb[base0 + (size_t)c * 5120] = o;
    r0 += v[c].x; r1 += v[c].y; r2 += v[c].z; r3 += v[c].w;
  }
}

// ---------------- Phase C: per-chunk attention output (MFMA, transposed) ----------
// R19: P/Vt strides 136->130 => LDS 56576->54080 B => 3 blocks/CU (was 2).
// R20: byte-identical resubmission — R19's run was clock-throttled (unchanged
// qkv slowed 16% with identical FETCH/WRITE), so the change was unmeasurable.
__global__ __launch_bounds__(256) void chunk_attn_kernel(
    const unsigned short* __restrict__ qh, const unsigned short* __restrict__ kh,
    const unsigned short* __restrict__ vh, const unsigned short* __restrict__ SPb,
    unsigned short* __restrict__ yb) {
  // region A: Qs[128][64]@0, Ks[128][64]@8192 (16384 shorts); P[128][PSTA]=16640
  // shorts overlays region A after Qs/Ks dead. Vt[80][VTSTA] @16640.
  __shared__ __align__(16) unsigned short lds[16640 + 80 * VTSTA];  // 54080 B
  unsigned short* Qs = lds;                       // [128][64] swizzled
  unsigned short* Ks = lds + 8192;                // [128][64] swizzled
  unsigned short* P  = lds;                       // [128][PSTA] (after Qs/Ks dead)
  unsigned short* Vt = lds + 16640;               // [80][VTSTA]

  int blk = blockIdx.x;
  int bh = blk / NCH, c = blk % NCH;
  int b = bh / HH, h = bh % HH;
  int tid = threadIdx.x;
  const unsigned short* qp = qh + ((size_t)bh * TT + c * LCH) * DD;
  const unsigned short* kp = kh + ((size_t)bh * TT + c * LCH) * DD;
  const unsigned short* vp = vh + ((size_t)bh * TT + c * LCH) * DD;

  int wave = tid >> 6, lane = tid & 63;
  int lr = lane & 15, lq = lane >> 4;
  int mbase = wave * 32;

  // 1) V -> regs first (oldest in vmcnt order)
  const int vt = tid & 127, vj0 = (tid >> 7) * 8;
  uint4 wv[4];
  #pragma unroll
  for (int ii = 0; ii < 4; ii++)
    wv[ii] = *(const uint4*)&vp[(size_t)vt * DD + vj0 + ii * 16];
  asm volatile("" ::: "memory");   // keep V loads issued before the gld_lds

  // 2) async Q,K -> LDS: wave stages rows [wave*32, +32) = 4 glds each.
  {
    const int grow8 = lane >> 3;               // 0..7
    const int gc = (lane & 7) ^ grow8;         // swizzled source 16B-chunk
    const unsigned short* gq = qp + (size_t)(wave * 32 + grow8) * DD + gc * 8;
    const unsigned short* gk = kp + (size_t)(wave * 32 + grow8) * DD + gc * 8;
    unsigned short* dq = Qs + wave * 32 * DD;  // wave-uniform dest
    unsigned short* dk = Ks + wave * 32 * DD;
    #pragma unroll
    for (int g = 0; g < 4; g++) {
      gld_lds_b128(gq + (size_t)g * 8 * DD, dq + g * 512);
      gld_lds_b128(gk + (size_t)g * 8 * DD, dk + g * 512);
    }
  }

  // 3) V transpose writes (compiler waits only the 4 V loads; 8 glds in flight)
  #pragma unroll
  for (int ii = 0; ii < 4; ii++) {
    union { uint4 u; unsigned short s[8]; } w; w.u = wv[ii];
    const int j8 = vj0 + ii * 16;
    #pragma unroll
    for (int jj = 0; jj < 8; jj++) Vt[(j8 + jj) * VTSTA + vt] = w.s[jj];
  }
  // ones row (j=64) and zero rows (65..79)
  for (int e = tid; e < 16 * 128; e += 256) {
    int rr = e >> 7, n = e & 127;
    Vt[(64 + rr) * VTSTA + n] = (rr == 0) ? (unsigned short)0x3F80 : (unsigned short)0;
  }
  asm volatile("s_waitcnt vmcnt(0)" ::: "memory");  // Q/K resident in LDS
  __syncthreads();

  // Q frags (swizzled chunk read) for this wave's two 16-row t-tiles
  bf16x8 aq[2][2];
  #pragma unroll
  for (int i = 0; i < 2; i++)
    #pragma unroll
    for (int kk = 0; kk < 2; kk++)
      aq[i][kk] = *(const bf16x8*)&Qs[(mbase + i * 16 + lr) * DD +
                                      ((((kk << 2) + lq) ^ (lr & 7)) << 3)];

  // accT[jt][it]: D[j][t], rows j = jt*16 + lq*4 + r, cols t = mbase + it*16 + lr
  floatx4 accT[5][2] = {};
  // inter-chunk: A = SPb rows [j][i], B = Q rows [t][i]
  const unsigned short* spb = SPb + (size_t)blk * (80 * 64);
  #pragma unroll
  for (int jt = 0; jt < 5; jt++)
    #pragma unroll
    for (int kk = 0; kk < 2; kk++) {
      bf16x8 asp = *(const bf16x8*)&spb[(jt * 16 + lr) * 64 + kk * 32 + lq * 8];
      accT[jt][0] = __builtin_amdgcn_mfma_f32_16x16x32_bf16(asp, aq[0][kk], accT[jt][0], 0, 0, 0);
      accT[jt][1] = __builtin_amdgcn_mfma_f32_16x16x32_bf16(asp, aq[1][kk], accT[jt][1], 0, 0, 0);
    }
  // intra-chunk scores: S = Q @ K^T (row=t(q), col=t'(k))
  floatx4 sacc[2][8] = {};
  #pragma unroll
  for (int nt = 0; nt < 8; nt++)
    #pragma unroll
    for (int kk = 0; kk < 2; kk++) {
      bf16x8 bk = *(const bf16x8*)&Ks[(nt * 16 + lr) * DD +
                                      ((((kk << 2) + lq) ^ (lr & 7)) << 3)];
      sacc[0][nt] = __builtin_amdgcn_mfma_f32_16x16x32_bf16(aq[0][kk], bk, sacc[0][nt], 0, 0, 0);
      sacc[1][nt] = __builtin_amdgcn_mfma_f32_16x16x32_bf16(aq[1][kk], bk, sacc[1][nt], 0, 0, 0);
    }
  __syncthreads();  // everyone done reading Qs/Ks before P overwrites them

  // causal mask + bf16 round, C-layout -> LDS P[t][t']
  #pragma unroll
  for (int i = 0; i < 2; i++)
    #pragma unroll
    for (int nt = 0; nt < 8; nt++) {
      int col = nt * 16 + lr;
      #pragma unroll
      for (int r = 0; r < 4; r++) {
        int m = mbase + i * 16 + lq * 4 + r;
        float v = (col <= m) ? sacc[i][nt][r] : 0.f;
        P[m * PSTA + col] = f2bf(v);
      }
    }
  __syncthreads();

  // accT += (P @ V_ext)^T: A = Vt rows [j][t'], B = P rows [t][t']
  #pragma unroll
  for (int kk4 = 0; kk4 < 4; kk4++) {
    bf16x8 bp0 = *(const bf16x8*)&P[(mbase + lr) * PSTA + kk4 * 32 + lq * 8];
    bf16x8 bp1 = *(const bf16x8*)&P[(mbase + 16 + lr) * PSTA + kk4 * 32 + lq * 8];
    #pragma unroll
    for (int jt = 0; jt < 5; jt++) {
      bf16x8 av = *(const bf16x8*)&Vt[(jt * 16 + lr) * VTSTA + kk4 * 32 + lq * 8];
      accT[jt][0] = __builtin_amdgcn_mfma_f32_16x16x32_bf16(av, bp0, accT[jt][0], 0, 0, 0);
      accT[jt][1] = __builtin_amdgcn_mfma_f32_16x16x32_bf16(av, bp1, accT[jt][1], 0, 0, 0);
    }
  }

  // epilogue: den = row 64 = accT[4][it] reg0 on lanes lq=0, col=t=lane&15.
  #pragma unroll
  for (int it = 0; it < 2; it++) {
    float den = __shfl(accT[4][it][0], lr, 64);
    float inv = 1.f / (den + EPSF);
    int tg = c * LCH + mbase + it * 16 + lr;
    size_t base = ((size_t)b * TT + tg) * CC + h * DD;
    #pragma unroll
    for (int jt = 0; jt < 4; jt++) {
      ushort4 o;
      o.x = f2bf(accT[jt][it][0] * inv);
      o.y = f2bf(accT[jt][it][1] * inv);
      o.z = f2bf(accT[jt][it][2] * inv);
      o.w = f2bf(accT[jt][it][3] * inv);
      *(ushort4*)&yb[base + jt * 16 + lq * 4] = o;
    }
  }
}

// ---------------- host launch ----------------
extern "C" void kernel_launch(void* const* d_in, const int* in_sizes, int n_in,
                              void* d_out, int out_size, void* d_ws, size_t ws_size,
                              hipStream_t stream) {
  const float* x      = (const float*)d_in[0];
  const float* W_attn = (const float*)d_in[1];
  const float* b_attn = (const float*)d_in[2];
  const float* W_proj = (const float*)d_in[3];
  const float* b_proj = (const float*)d_in[4];
  float* out = (float*)d_out;

  char* ws = (char*)d_ws;
  size_t off = 0;
  auto alloc = [&](size_t bytes) -> char* {
    char* p = ws + off;
    off += (bytes + 255) & ~(size_t)255;
    return p;
  };
  unsigned short* xb  = (unsigned short*)alloc((size_t)MM * CC * 2);   // reused as yb
  unsigned short* WaT = (unsigned short*)alloc((size_t)NQKV * CC * 2);
  unsigned short* WpT = (unsigned short*)alloc((size_t)CC * CC * 2);
  unsigned short* qh  = (unsigned short*)alloc((size_t)MM * CC * 2);
  unsigned short* kh  = (unsigned short*)alloc((size_t)MM * CC * 2);
  unsigned short* vh  = (unsigned short*)alloc((size_t)MM * CC * 2);
  float* KVx = (float*)alloc((size_t)BB * HH * NCH * 80 * 64 * 4);
  unsigned short* SPb = (unsigned short*)alloc((size_t)BB * HH * NCH * 80 * 64 * 2);
  unsigned short* yb = xb;  // xb dead after gemm_qkv

  static bool s_attr_done = false;
  if (!s_attr_done) {
    (void)hipFuncSetAttribute((const void*)gemm_qkv_kernel,
                              hipFuncAttributeMaxDynamicSharedMemorySize, 114688);
    (void)hipFuncSetAttribute((const void*)gemm_proj_kernel,
                              hipFuncAttributeMaxDynamicSharedMemorySize, 98304);
    s_attr_done = true;
  }

  prep_kernel<<<12288, 256, 0, stream>>>(x, xb, W_attn, WaT, W_proj, WpT);
  gemm_qkv_kernel<<<dim3(NQKV / 192, MM / 256), 512, 114688, stream>>>(xb, WaT, b_attn, qh, kh, vh);
  chunk_state_kernel<<<BB * HH * NCH, 256, 0, stream>>>(kh, vh, KVx);
  prefix_state_kernel<<<BB * HH * 5, 256, 0, stream>>>(KVx, SPb);
  chunk_attn_kernel<<<BB * HH * NCH, 256, 0, stream>>>(qh, kh, vh, SPb, yb);
  gemm_proj_kernel<<<dim3(CC / 256, MM / 128), 512, 98304, stream>>>(yb, WpT, b_proj, out);
}

// Round 13
// 216.473 us; speedup vs baseline: 1.0991x; 1.0546x over previous
//
#include <hip/hip_runtime.h>
#include <math.h>

// Problem constants (reference: B=4, T=2048, C=1024, H=16, d=64)
#define BB   4
#define TT   2048
#define CC   1024
#define HH   16
#define DD   64
#define MM   (BB*TT)     // 8192 rows
#define NQKV (3*CC)      // 3072
#define LCH  128         // attention chunk length
#define NCH  (TT/LCH)    // 16 chunks per (b,h)
#define EPSF 1e-6f

// LDS strides (in shorts) for attention kernels — padded to break bank aliasing.
// R21: chunk_attn reverted to 136 (R19/R20 measured stride-130 = net negative:
// LDS-read aliasing on the barrier-chain critical path outweighed +1 block/CU).
#define PST  136         // P tile row stride
#define VTST 136         // V-transposed tile row stride

typedef __bf16 bf16x8 __attribute__((ext_vector_type(8)));
typedef float  floatx4 __attribute__((ext_vector_type(4)));

__device__ __forceinline__ unsigned short f2bf(float f) {
  union { float f; unsigned int u; } v; v.f = f;
  unsigned int r = v.u + 0x7fffu + ((v.u >> 16) & 1u); // RNE
  return (unsigned short)(r >> 16);
}
__device__ __forceinline__ float bf2f(unsigned short s) {
  union { unsigned int u; float f; } v; v.u = ((unsigned int)s) << 16;
  return v.f;
}
__device__ __forceinline__ float featmap(float v) {
  // elu(v)+1
  return v > 0.f ? v + 1.f : __expf(v);
}
// async global->LDS, 16B per lane; LDS dest = wave-uniform base + lane*16
__device__ __forceinline__ void gld_lds_b128(const unsigned short* g, unsigned short* l) {
  __builtin_amdgcn_global_load_lds(
      (const __attribute__((address_space(1))) unsigned int*)g,
      (__attribute__((address_space(3))) unsigned int*)l, 16, 0, 0);
}

// ---------------- prep: x->bf16 + both weight transposes, one kernel ----------------
// R18 vectorized transpose body (measured neutral vs scalar; kept — G13-sound).
__device__ __forceinline__ void transpose_cvt_body(const float* __restrict__ W,
                                                   unsigned short* __restrict__ out,
                                                   int R, int Cc, int bx32, int by32, int tid) {
  __shared__ float tile[32][33];
  int bx = bx32 * 32, by = by32 * 32;
  {
    int r = tid >> 3, c4 = tid & 7;
    float4 f = *(const float4*)&W[(size_t)(by + r) * Cc + bx + c4 * 4];
    tile[r][c4 * 4 + 0] = f.x; tile[r][c4 * 4 + 1] = f.y;
    tile[r][c4 * 4 + 2] = f.z; tile[r][c4 * 4 + 3] = f.w;
  }
  __syncthreads();
  {
    int i = tid >> 3, t4 = tid & 7;
    ushort4 o;
    o.x = f2bf(tile[t4 * 4 + 0][i]);
    o.y = f2bf(tile[t4 * 4 + 1][i]);
    o.z = f2bf(tile[t4 * 4 + 2][i]);
    o.w = f2bf(tile[t4 * 4 + 3][i]);
    *(ushort4*)&out[(size_t)(bx + i) * R + by + t4 * 4] = o;
  }
}

// grid: [0,8192) cvt_x | [8192,11264) W_attn transpose | [11264,12288) W_proj transpose
__global__ __launch_bounds__(256) void prep_kernel(
    const float* __restrict__ x, unsigned short* __restrict__ xb,
    const float* __restrict__ Wa, unsigned short* __restrict__ WaT,
    const float* __restrict__ Wp, unsigned short* __restrict__ WpT) {
  int blk = blockIdx.x, tid = threadIdx.x;
  if (blk < 8192) {
    int i = (blk * 256 + tid) * 4;
    float4 f = *(const float4*)(x + i);
    ushort4 o;
    o.x = f2bf(f.x); o.y = f2bf(f.y); o.z = f2bf(f.z); o.w = f2bf(f.w);
    *(ushort4*)(xb + i) = o;
  } else if (blk < 8192 + 3072) {
    int t = blk - 8192;                       // 96 x 32
    transpose_cvt_body(Wa, WaT, CC, NQKV, t % 96, t / 96, tid);
  } else {
    int t = blk - 11264;                      // 32 x 32
    transpose_cvt_body(Wp, WpT, CC, CC, t % 32, t / 32, tid);
  }
}

// ---------------- GEMM 1: qkv = x @ W_attn + b, split + feature map ----------------
// R11 schedule + T1 XCD-chunked block swizzle (verified: FETCH 71.8->57.5MB).
#define BKQ   32
#define ASLT  (256 * BKQ)   // 8192 shorts / slot
#define BSLT  (192 * BKQ)   // 6144 shorts / slot
#define NT_Q  (CC / BKQ)    // 32 K-tiles

__global__ __launch_bounds__(512, 2) void gemm_qkv_kernel(
    const unsigned short* __restrict__ A, const unsigned short* __restrict__ Bt,
    const float* __restrict__ bias,
    unsigned short* __restrict__ qh, unsigned short* __restrict__ kh,
    unsigned short* __restrict__ vh) {
  extern __shared__ __align__(16) unsigned short lds[];
  unsigned short* Ar = lds;                 // [4][256][32]
  unsigned short* Br = lds + 4 * ASLT;      // [4][192][32]

  const int tid = threadIdx.x;
  const int wave = tid >> 6, lane = tid & 63;
  const int lr = lane & 15, lq = lane >> 4;
  // T1 swizzle: lin = y*16+x (HW x-fastest); XCD k owns 64 consecutive new ids.
  const int lin = blockIdx.y * 16 + blockIdx.x;
  const int lin2 = (lin & 7) * 64 + (lin >> 3);
  const int m0 = (lin2 >> 4) * 256, n0 = (lin2 & 15) * 192;
  const int wm = (wave >> 2) * 128, wn = (wave & 3) * 48;

  const int srow = wave * 16 + (lane >> 2);
  const int cs = (lane & 3) ^ ((lane >> 3) & 3);
  const unsigned short* gA0 = A  + (size_t)(m0 + srow) * CC + cs * 8;
  const unsigned short* gB0 = Bt + (size_t)(n0 + srow) * CC + cs * 8;
  unsigned short* const stA = Ar + wave * 512;   // wave-uniform LDS dest base
  unsigned short* const stB = Br + wave * 512;
  const bool bhi = (wave < 4);                   // waves 0-3 stage B rows 128..191

  const int chunk = lq ^ ((lr >> 1) & 3);
  const int roA = (wm + lr) * BKQ + chunk * 8;
  const int roB = (wn + lr) * BKQ + chunk * 8;

  floatx4 acc[3][8] = {};   // [n-frag][m-frag], transposed-C convention

#define QSTAGE_A(tt) do {                                      \
    const unsigned short* g_ = gA0 + (tt) * BKQ;               \
    unsigned short* d_ = stA + ((tt) & 3) * ASLT;              \
    gld_lds_b128(g_, d_);                                      \
    gld_lds_b128(g_ + (size_t)128 * CC, d_ + 4096);            \
  } while (0)
#define QSTAGE_B(tt) do {                                      \
    const unsigned short* g_ = gB0 + (tt) * BKQ;               \
    unsigned short* d_ = stB + ((tt) & 3) * BSLT;              \
    gld_lds_b128(g_, d_);                                      \
    if (bhi) gld_lds_b128(g_ + (size_t)128 * CC, d_ + 4096);   \
  } while (0)

  // prologue: stage K-tiles 0,1,2; wait tile 0 (keep tiles 1,2 in flight)
  QSTAGE_A(0); QSTAGE_B(0);
  QSTAGE_A(1); QSTAGE_B(1);
  QSTAGE_A(2); QSTAGE_B(2);
  asm volatile("s_waitcnt vmcnt(6)" ::: "memory");
  __builtin_amdgcn_s_barrier();

  #pragma unroll 4
  for (int t = 0; t < NT_Q; ++t) {
    const unsigned short* sA = Ar + (t & 3) * ASLT + roA;
    const unsigned short* sB = Br + (t & 3) * BSLT + roB;
    bf16x8 an[3], bm[8];
    #pragma unroll
    for (int i = 0; i < 3; i++) an[i] = *(const bf16x8*)(sB + i * (16 * BKQ));
    #pragma unroll
    for (int j = 0; j < 8; j++) bm[j] = *(const bf16x8*)(sA + j * (16 * BKQ));
    if (t < NT_Q - 3) { QSTAGE_A(t + 3); QSTAGE_B(t + 3); }
    __builtin_amdgcn_s_barrier();
    asm volatile("s_waitcnt lgkmcnt(0)" ::: "memory");
    __builtin_amdgcn_s_setprio(1);
    #pragma unroll
    for (int i = 0; i < 3; i++)
      #pragma unroll
      for (int j = 0; j < 8; j++)
        acc[i][j] = __builtin_amdgcn_mfma_f32_16x16x32_bf16(an[i], bm[j], acc[i][j], 0, 0, 0);
    __builtin_amdgcn_s_setprio(0);
    // boundary: next tile's data must be resident; counted (never 0 until drain)
    if (t < NT_Q - 3)        asm volatile("s_waitcnt vmcnt(6)" ::: "memory");
    else if (t == NT_Q - 3)  asm volatile("s_waitcnt vmcnt(3)" ::: "memory");
    else if (t == NT_Q - 2)  asm volatile("s_waitcnt vmcnt(0)" ::: "memory");
    __builtin_amdgcn_s_barrier();
  }
#undef QSTAGE_A
#undef QSTAGE_B

  // epilogue: transposed C/D -> lane holds 4 consecutive n (channels), m = col.
  unsigned short* dstv[3];
  size_t qoff[3];
  float4 bi[3];
  bool feat[3];
  #pragma unroll
  for (int i = 0; i < 3; i++) {
    const int n = n0 + wn + i * 16 + lq * 4;
    dstv[i] = (n < 1024) ? qh : (n < 2048) ? kh : vh;
    feat[i] = (n < 2048);
    const int h = (n & 1023) >> 6, dd = n & 63;
    qoff[i] = (size_t)h * (TT * DD) + dd;
    bi[i] = *(const float4*)&bias[n];
  }
  #pragma unroll
  for (int j = 0; j < 8; j++) {
    const int m = m0 + wm + j * 16 + lr;
    const int b = m >> 11, tg = m & 2047;
    const size_t pj = (size_t)b * (HH * TT * DD) + (size_t)tg * DD;
    #pragma unroll
    for (int i = 0; i < 3; i++) {
      float v0 = acc[i][j][0] + bi[i].x, v1 = acc[i][j][1] + bi[i].y;
      float v2 = acc[i][j][2] + bi[i].z, v3 = acc[i][j][3] + bi[i].w;
      if (feat[i]) { v0 = featmap(v0); v1 = featmap(v1); v2 = featmap(v2); v3 = featmap(v3); }
      ushort4 o; o.x = f2bf(v0); o.y = f2bf(v1); o.z = f2bf(v2); o.w = f2bf(v3);
      *(ushort4*)&dstv[i][pj + qoff[i]] = o;
    }
  }
}

// ---------------- GEMM 2: out = y @ W_proj + b_proj (fp32 out) ----------------
// R12 schedule + T1 swizzle (grid 4x64 = 256 = 8 XCDs x 32, bijective).
#define PBK   32
#define PASLT (128 * PBK)   // 4096 shorts / slot
#define PBSLT (256 * PBK)   // 8192 shorts / slot
#define NT_P  (CC / PBK)    // 32 K-tiles

__global__ __launch_bounds__(512, 2) void gemm_proj_kernel(
    const unsigned short* __restrict__ A, const unsigned short* __restrict__ Bt,
    const float* __restrict__ bias, float* __restrict__ out) {
  extern __shared__ __align__(16) unsigned short lds[];
  unsigned short* Ar = lds;                 // [4][128][32]
  unsigned short* Br = lds + 4 * PASLT;     // [4][256][32]

  const int tid = threadIdx.x;
  const int wave = tid >> 6, lane = tid & 63;
  const int lr = lane & 15, lq = lane >> 4;
  const int lin = blockIdx.y * 4 + blockIdx.x;
  const int lin2 = (lin & 7) * 32 + (lin >> 3);
  const int m0 = (lin2 >> 2) * 128, n0 = (lin2 & 3) * 256;
  const int wm = (wave >> 2) * 64, wn = (wave & 3) * 64;

  const int srow = wave * 16 + (lane >> 2);
  const int cs = (lane & 3) ^ ((lane >> 3) & 3);
  const unsigned short* gA0 = A  + (size_t)(m0 + srow) * CC + cs * 8;
  const unsigned short* gB0 = Bt + (size_t)(n0 + srow) * CC + cs * 8;
  unsigned short* const stA = Ar + wave * 512;
  unsigned short* const stB = Br + wave * 512;

  const int chunk = lq ^ ((lr >> 1) & 3);
  const int roA = (wm + lr) * PBK + chunk * 8;
  const int roB = (wn + lr) * PBK + chunk * 8;

  floatx4 acc[4][4] = {};   // [n-frag][m-frag], transposed-C convention

#define PSTAGE(tt) do {                                        \
    const unsigned short* ga_ = gA0 + (tt) * PBK;              \
    unsigned short* da_ = stA + ((tt) & 3) * PASLT;            \
    gld_lds_b128(ga_, da_);                                    \
    const unsigned short* gb_ = gB0 + (tt) * PBK;              \
    unsigned short* db_ = stB + ((tt) & 3) * PBSLT;            \
    gld_lds_b128(gb_, db_);                                    \
    gld_lds_b128(gb_ + (size_t)128 * CC, db_ + 4096);          \
  } while (0)

  PSTAGE(0); PSTAGE(1); PSTAGE(2);
  asm volatile("s_waitcnt vmcnt(6)" ::: "memory");
  __builtin_amdgcn_s_barrier();

  #pragma unroll 4
  for (int t = 0; t < NT_P; ++t) {
    const unsigned short* sA = Ar + (t & 3) * PASLT + roA;
    const unsigned short* sB = Br + (t & 3) * PBSLT + roB;
    bf16x8 an[4], bm[4];
    #pragma unroll
    for (int i = 0; i < 4; i++) an[i] = *(const bf16x8*)(sB + i * (16 * PBK));
    #pragma unroll
    for (int j = 0; j < 4; j++) bm[j] = *(const bf16x8*)(sA + j * (16 * PBK));
    if (t < NT_P - 3) PSTAGE(t + 3);
    __builtin_amdgcn_s_barrier();
    asm volatile("s_waitcnt lgkmcnt(0)" ::: "memory");
    __builtin_amdgcn_s_setprio(1);
    #pragma unroll
    for (int i = 0; i < 4; i++)
      #pragma unroll
      for (int j = 0; j < 4; j++)
        acc[i][j] = __builtin_amdgcn_mfma_f32_16x16x32_bf16(an[i], bm[j], acc[i][j], 0, 0, 0);
    __builtin_amdgcn_s_setprio(0);
    if (t < NT_P - 3)        asm volatile("s_waitcnt vmcnt(6)" ::: "memory");
    else if (t == NT_P - 3)  asm volatile("s_waitcnt vmcnt(3)" ::: "memory");
    else if (t == NT_P - 2)  asm volatile("s_waitcnt vmcnt(0)" ::: "memory");
    __builtin_amdgcn_s_barrier();
  }
#undef PSTAGE

  // epilogue: lane holds 4 consecutive n; m = col (lr). float4 stores + bias.
  #pragma unroll
  for (int i = 0; i < 4; i++) {
    const int n = n0 + wn + i * 16 + lq * 4;
    const float4 bi = *(const float4*)&bias[n];
    #pragma unroll
    for (int j = 0; j < 4; j++) {
      const int m = m0 + wm + j * 16 + lr;
      float4 o;
      o.x = acc[i][j][0] + bi.x; o.y = acc[i][j][1] + bi.y;
      o.z = acc[i][j][2] + bi.z; o.w = acc[i][j][3] + bi.w;
      *(float4*)&out[(size_t)m * CC + n] = o;
    }
  }
}

// ---------------- Phase A: per-chunk KV state (MFMA) ----------------
// R15 version (issue-early, full column coverage).
__global__ __launch_bounds__(256) void chunk_state_kernel(
    const unsigned short* __restrict__ kh, const unsigned short* __restrict__ vh,
    float* __restrict__ KVx) {
  __shared__ __align__(16) unsigned short Kt[64 * VTST];   // K^T: Kt[i][t]
  __shared__ __align__(16) unsigned short Vt[80 * VTST];   // V^T + ones/zero rows
  int blk = blockIdx.x;
  int bh = blk / NCH, c = blk % NCH;
  int tid = threadIdx.x;
  const unsigned short* kp = kh + ((size_t)bh * TT + c * LCH) * DD;
  const unsigned short* vp = vh + ((size_t)bh * TT + c * LCH) * DD;
  {
    int t = tid & 127, j0 = (tid >> 7) * 8;
    union { uint4 u; unsigned short s[8]; } wk[4], wv[4];
    #pragma unroll
    for (int ii = 0; ii < 4; ii++) {
      wk[ii].u = *(const uint4*)&kp[(size_t)t * DD + j0 + ii * 16];
      wv[ii].u = *(const uint4*)&vp[(size_t)t * DD + j0 + ii * 16];
    }
    #pragma unroll
    for (int ii = 0; ii < 4; ii++) {
      const int j8 = j0 + ii * 16;
      #pragma unroll
      for (int jj = 0; jj < 8; jj++) {
        Kt[(j8 + jj) * VTST + t] = wk[ii].s[jj];
        Vt[(j8 + jj) * VTST + t] = wv[ii].s[jj];
      }
    }
  }
  for (int e = tid; e < 16 * 128; e += 256) {
    int rr = e >> 7, n = e & 127;
    Vt[(64 + rr) * VTST + n] = (rr == 0) ? (unsigned short)0x3F80 : (unsigned short)0;
  }
  __syncthreads();
  int wave = tid >> 6, lane = tid & 63;
  int lr = lane & 15, lq = lane >> 4;
  int i0 = wave * 16;             // wave's 16-row band of K^T (i dimension)
  floatx4 acc[5] = {};
  #pragma unroll
  for (int kk = 0; kk < 4; kk++) {
    bf16x8 a = *(const bf16x8*)&Kt[(i0 + lr) * VTST + kk * 32 + lq * 8];
    #pragma unroll
    for (int jt = 0; jt < 5; jt++) {
      bf16x8 b = *(const bf16x8*)&Vt[(jt * 16 + lr) * VTST + kk * 32 + lq * 8];
      acc[jt] = __builtin_amdgcn_mfma_f32_16x16x32_bf16(a, b, acc[jt], 0, 0, 0);
    }
  }
  // C/D: col(j) = lane&15, row(i) = i0 + lq*4 + r; store transposed [j][i].
  float* o = KVx + (size_t)blk * 5120;
  #pragma unroll
  for (int jt = 0; jt < 5; jt++)
    *(float4*)&o[(jt * 16 + lr) * 64 + i0 + lq * 4] = *(float4*)&acc[jt];
}

// ---------------- Phase B: exclusive prefix over chunks -> bf16 SP_ext ----------
// R11: fully unrolled — all 16 chunk loads issued up front, then scan+stores.
__global__ __launch_bounds__(256) void prefix_state_kernel(const float* __restrict__ KVx,
                                                           unsigned short* __restrict__ SPb) {
  int bh = blockIdx.x / 5, jb = blockIdx.x % 5;
  int e = jb * 1024 + threadIdx.x * 4;
  size_t base0 = ((size_t)bh * NCH) * 5120 + e;
  float4 v[NCH];
  #pragma unroll
  for (int c = 0; c < NCH; c++)
    v[c] = *(const float4*)&KVx[base0 + (size_t)c * 5120];
  float r0 = 0.f, r1 = 0.f, r2 = 0.f, r3 = 0.f;
  #pragma unroll
  for (int c = 0; c < NCH; c++) {
    ushort4 o;
    o.x = f2bf(r0); o.y = f2bf(r1); o.z = f2bf(r2); o.w = f2bf(r3);
    *(ushort4*)&SPb[base0 + (size_t)c * 5120] = o;
    r0 += v[c].x; r1 += v[c].y; r2 += v[c].z; r3 += v[c].w;
  }
}

// ---------------- Phase C: per-chunk attention output (MFMA, transposed) ----------
// R21: reverted to R18/R15 exact (stride 136, 2 blocks/CU) — the best-measured
// config. R19/R20's stride-130 3-blocks/CU variant measured ~6µs worse after
// chip-speed normalization (LDS aliasing on the barrier-chain critical path).
__global__ __launch_bounds__(256) void chunk_attn_kernel(
    const unsigned short* __restrict__ qh, const unsigned short* __restrict__ kh,
    const unsigned short* __restrict__ vh, const unsigned short* __restrict__ SPb,
    unsigned short* __restrict__ yb) {
  __shared__ __align__(16) unsigned short lds[17408 + 80 * VTST];  // 56576 B
  unsigned short* Qs = lds;                       // [128][64] swizzled
  unsigned short* Ks = lds + 8192;                // [128][64] swizzled
  unsigned short* P  = lds;                       // [128][PST] (after Qs/Ks dead)
  unsigned short* Vt = lds + 17408;               // [80][VTST]

  int blk = blockIdx.x;
  int bh = blk / NCH, c = blk % NCH;
  int b = bh / HH, h = bh % HH;
  int tid = threadIdx.x;
  const unsigned short* qp = qh + ((size_t)bh * TT + c * LCH) * DD;
  const unsigned short* kp = kh + ((size_t)bh * TT + c * LCH) * DD;
  const unsigned short* vp = vh + ((size_t)bh * TT + c * LCH) * DD;

  int wave = tid >> 6, lane = tid & 63;
  int lr = lane & 15, lq = lane >> 4;
  int mbase = wave * 32;

  // 1) V -> regs first (oldest in vmcnt order)
  const int vt = tid & 127, vj0 = (tid >> 7) * 8;
  uint4 wv[4];
  #pragma unroll
  for (int ii = 0; ii < 4; ii++)
    wv[ii] = *(const uint4*)&vp[(size_t)vt * DD + vj0 + ii * 16];
  asm volatile("" ::: "memory");   // keep V loads issued before the gld_lds

  // 2) async Q,K -> LDS: wave stages rows [wave*32, +32) = 4 glds each.
  {
    const int grow8 = lane >> 3;               // 0..7
    const int gc = (lane & 7) ^ grow8;         // swizzled source 16B-chunk
    const unsigned short* gq = qp + (size_t)(wave * 32 + grow8) * DD + gc * 8;
    const unsigned short* gk = kp + (size_t)(wave * 32 + grow8) * DD + gc * 8;
    unsigned short* dq = Qs + wave * 32 * DD;  // wave-uniform dest
    unsigned short* dk = Ks + wave * 32 * DD;
    #pragma unroll
    for (int g = 0; g < 4; g++) {
      gld_lds_b128(gq + (size_t)g * 8 * DD, dq + g * 512);
      gld_lds_b128(gk + (size_t)g * 8 * DD, dk + g * 512);
    }
  }

  // 3) V transpose writes (compiler waits only the 4 V loads; 8 glds in flight)
  #pragma unroll
  for (int ii = 0; ii < 4; ii++) {
    union { uint4 u; unsigned short s[8]; } w; w.u = wv[ii];
    const int j8 = vj0 + ii * 16;
    #pragma unroll
    for (int jj = 0; jj < 8; jj++) Vt[(j8 + jj) * VTST + vt] = w.s[jj];
  }
  // ones row (j=64) and zero rows (65..79)
  for (int e = tid; e < 16 * 128; e += 256) {
    int rr = e >> 7, n = e & 127;
    Vt[(64 + rr) * VTST + n] = (rr == 0) ? (unsigned short)0x3F80 : (unsigned short)0;
  }
  asm volatile("s_waitcnt vmcnt(0)" ::: "memory");  // Q/K resident in LDS
  __syncthreads();

  // Q frags (swizzled chunk read) for this wave's two 16-row t-tiles
  bf16x8 aq[2][2];
  #pragma unroll
  for (int i = 0; i < 2; i++)
    #pragma unroll
    for (int kk = 0; kk < 2; kk++)
      aq[i][kk] = *(const bf16x8*)&Qs[(mbase + i * 16 + lr) * DD +
                                      ((((kk << 2) + lq) ^ (lr & 7)) << 3)];

  // accT[jt][it]: D[j][t], rows j = jt*16 + lq*4 + r, cols t = mbase + it*16 + lr
  floatx4 accT[5][2] = {};
  // inter-chunk: A = SPb rows [j][i], B = Q rows [t][i]
  const unsigned short* spb = SPb + (size_t)blk * (80 * 64);
  #pragma unroll
  for (int jt = 0; jt < 5; jt++)
    #pragma unroll
    for (int kk = 0; kk < 2; kk++) {
      bf16x8 asp = *(const bf16x8*)&spb[(jt * 16 + lr) * 64 + kk * 32 + lq * 8];
      accT[jt][0] = __builtin_amdgcn_mfma_f32_16x16x32_bf16(asp, aq[0][kk], accT[jt][0], 0, 0, 0);
      accT[jt][1] = __builtin_amdgcn_mfma_f32_16x16x32_bf16(asp, aq[1][kk], accT[jt][1], 0, 0, 0);
    }
  // intra-chunk scores: S = Q @ K^T (row=t(q), col=t'(k))
  floatx4 sacc[2][8] = {};
  #pragma unroll
  for (int nt = 0; nt < 8; nt++)
    #pragma unroll
    for (int kk = 0; kk < 2; kk++) {
      bf16x8 bk = *(const bf16x8*)&Ks[(nt * 16 + lr) * DD +
                                      ((((kk << 2) + lq) ^ (lr & 7)) << 3)];
      sacc[0][nt] = __builtin_amdgcn_mfma_f32_16x16x32_bf16(aq[0][kk], bk, sacc[0][nt], 0, 0, 0);
      sacc[1][nt] = __builtin_amdgcn_mfma_f32_16x16x32_bf16(aq[1][kk], bk, sacc[1][nt], 0, 0, 0);
    }
  __syncthreads();  // everyone done reading Qs/Ks before P overwrites them

  // causal mask + bf16 round, C-layout -> LDS P[t][t']
  #pragma unroll
  for (int i = 0; i < 2; i++)
    #pragma unroll
    for (int nt = 0; nt < 8; nt++) {
      int col = nt * 16 + lr;
      #pragma unroll
      for (int r = 0; r < 4; r++) {
        int m = mbase + i * 16 + lq * 4 + r;
        float v = (col <= m) ? sacc[i][nt][r] : 0.f;
        P[m * PST + col] = f2bf(v);
      }
    }
  __syncthreads();

  // accT += (P @ V_ext)^T: A = Vt rows [j][t'], B = P rows [t][t']
  #pragma unroll
  for (int kk4 = 0; kk4 < 4; kk4++) {
    bf16x8 bp0 = *(const bf16x8*)&P[(mbase + lr) * PST + kk4 * 32 + lq * 8];
    bf16x8 bp1 = *(const bf16x8*)&P[(mbase + 16 + lr) * PST + kk4 * 32 + lq * 8];
    #pragma unroll
    for (int jt = 0; jt < 5; jt++) {
      bf16x8 av = *(const bf16x8*)&Vt[(jt * 16 + lr) * VTST + kk4 * 32 + lq * 8];
      accT[jt][0] = __builtin_amdgcn_mfma_f32_16x16x32_bf16(av, bp0, accT[jt][0], 0, 0, 0);
      accT[jt][1] = __builtin_amdgcn_mfma_f32_16x16x32_bf16(av, bp1, accT[jt][1], 0, 0, 0);
    }
  }

  // epilogue: den = row 64 = accT[4][it] reg0 on lanes lq=0, col=t=lane&15.
  #pragma unroll
  for (int it = 0; it < 2; it++) {
    float den = __shfl(accT[4][it][0], lr, 64);
    float inv = 1.f / (den + EPSF);
    int tg = c * LCH + mbase + it * 16 + lr;
    size_t base = ((size_t)b * TT + tg) * CC + h * DD;
    #pragma unroll
    for (int jt = 0; jt < 4; jt++) {
      ushort4 o;
      o.x = f2bf(accT[jt][it][0] * inv);
      o.y = f2bf(accT[jt][it][1] * inv);
      o.z = f2bf(accT[jt][it][2] * inv);
      o.w = f2bf(accT[jt][it][3] * inv);
      *(ushort4*)&yb[base + jt * 16 + lq * 4] = o;
    }
  }
}

// ---------------- host launch ----------------
extern "C" void kernel_launch(void* const* d_in, const int* in_sizes, int n_in,
                              void* d_out, int out_size, void* d_ws, size_t ws_size,
                              hipStream_t stream) {
  const float* x      = (const float*)d_in[0];
  const float* W_attn = (const float*)d_in[1];
  const float* b_attn = (const float*)d_in[2];
  const float* W_proj = (const float*)d_in[3];
  const float* b_proj = (const float*)d_in[4];
  float* out = (float*)d_out;

  char* ws = (char*)d_ws;
  size_t off = 0;
  auto alloc = [&](size_t bytes) -> char* {
    char* p = ws + off;
    off += (bytes + 255) & ~(size_t)255;
    return p;
  };
  unsigned short* xb  = (unsigned short*)alloc((size_t)MM * CC * 2);   // reused as yb
  unsigned short* WaT = (unsigned short*)alloc((size_t)NQKV * CC * 2);
  unsigned short* WpT = (unsigned short*)alloc((size_t)CC * CC * 2);
  unsigned short* qh  = (unsigned short*)alloc((size_t)MM * CC * 2);
  unsigned short* kh  = (unsigned short*)alloc((size_t)MM * CC * 2);
  unsigned short* vh  = (unsigned short*)alloc((size_t)MM * CC * 2);
  float* KVx = (float*)alloc((size_t)BB * HH * NCH * 80 * 64 * 4);
  unsigned short* SPb = (unsigned short*)alloc((size_t)BB * HH * NCH * 80 * 64 * 2);
  unsigned short* yb = xb;  // xb dead after gemm_qkv

  static bool s_attr_done = false;
  if (!s_attr_done) {
    (void)hipFuncSetAttribute((const void*)gemm_qkv_kernel,
                              hipFuncAttributeMaxDynamicSharedMemorySize, 114688);
    (void)hipFuncSetAttribute((const void*)gemm_proj_kernel,
                              hipFuncAttributeMaxDynamicSharedMemorySize, 98304);
    s_attr_done = true;
  }

  prep_kernel<<<12288, 256, 0, stream>>>(x, xb, W_attn, WaT, W_proj, WpT);
  gemm_qkv_kernel<<<dim3(NQKV / 192, MM / 256), 512, 114688, stream>>>(xb, WaT, b_attn, qh, kh, vh);
  chunk_state_kernel<<<BB * HH * NCH, 256, 0, stream>>>(kh, vh, KVx);
  prefix_state_kernel<<<BB * HH * 5, 256, 0, stream>>>(KVx, SPb);
  chunk_attn_kernel<<<BB * HH * NCH, 256, 0, stream>>>(qh, kh, vh, SPb, yb);
  gemm_proj_kernel<<<dim3(CC / 256, MM / 128), 512, 98304, stream>>>(yb, WpT, b_proj, out);
}